// Round 13
// baseline (266.676 us; speedup 1.0000x reference)
//
#include <hip/hip_runtime.h>
#include <stdint.h>

#define DIM 256
#define NPOS 4096
#define NB 4
#define GROUPS 32

typedef __attribute__((ext_vector_type(8))) short short8;
typedef __attribute__((ext_vector_type(4))) short short4v;
typedef __attribute__((ext_vector_type(4))) float f32x4;
typedef __attribute__((ext_vector_type(16))) float f32x16;
typedef __attribute__((ext_vector_type(2))) unsigned int u32x2;
typedef __attribute__((ext_vector_type(4))) unsigned int u32x4;

__device__ __forceinline__ short f2b(float f) {
  unsigned u = __float_as_uint(f);
  unsigned r = (u + 0x7fffu + ((u >> 16) & 1u)) >> 16;
  return (short)r;
}

__device__ __forceinline__ void gl16(const short* g, char* lds) {
  __builtin_amdgcn_global_load_lds((const __attribute__((address_space(1))) void*)g,
                                   (__attribute__((address_space(3))) void*)lds, 16, 0, 0);
}

// ---------------- weight conversion (f32 -> bf16) ----------------
__global__ void k_convert_w(const float* __restrict__ wq, const float* __restrict__ wp,
                            short* __restrict__ wqb, short* __restrict__ wpb) {
  int i = blockIdx.x * 256 + threadIdx.x;
  if (i < 768 * 256) wqb[i] = f2b(wq[i]);
  if (i < 256 * 256) wpb[i] = f2b(wp[i]);
}

// ---------------- GroupNorm stats: one block per (b,g) ----------------
__global__ void k_gn_stats(const float* __restrict__ x, float* __restrict__ stats) {
  int bg = blockIdx.x;
  const float4* b4 = (const float4*)(x + (size_t)bg * 8 * NPOS);
  float s = 0.f, ss = 0.f;
  for (int i = threadIdx.x; i < 8192; i += 256) {
    float4 v = b4[i];
    s  += v.x + v.y + v.z + v.w;
    ss += v.x * v.x + v.y * v.y + v.z * v.z + v.w * v.w;
  }
  #pragma unroll
  for (int m = 1; m < 64; m <<= 1) { s += __shfl_xor(s, m, 64); ss += __shfl_xor(ss, m, 64); }
  __shared__ float red[8];
  int wid = threadIdx.x >> 6;
  if ((threadIdx.x & 63) == 0) { red[wid * 2] = s; red[wid * 2 + 1] = ss; }
  __syncthreads();
  if (threadIdx.x == 0) {
    float S = red[0] + red[2] + red[4] + red[6];
    float SS = red[1] + red[3] + red[5] + red[7];
    float mean = S / 32768.f;
    float var = SS / 32768.f - mean * mean;
    stats[bg * 2] = mean;
    stats[bg * 2 + 1] = rsqrtf(var + 1e-6f);
  }
}

// ------------- GroupNorm apply + transpose: x(B,C,N) f32 -> h_t(B,N,C) bf16 -------------
__global__ void k_gn_apply(const float* __restrict__ x, const float* __restrict__ stats,
                           const float* __restrict__ gamma, const float* __restrict__ beta,
                           short* __restrict__ ht) {
  int ct = blockIdx.x, nt = blockIdx.y, b = blockIdx.z;
  int c0 = ct * 64, n0 = nt * 64;
  __shared__ short lt[64 * 72];
  int t = threadIdx.x;
  #pragma unroll
  for (int p = 0; p < 4; ++p) {
    int row = (t >> 4) + p * 16;
    int colb = (t & 15) * 4;
    int c = c0 + row;
    float mean = stats[(b * GROUPS + (c >> 3)) * 2];
    float rstd = stats[(b * GROUPS + (c >> 3)) * 2 + 1];
    float ga = gamma[c], be = beta[c];
    float4 v = *(const float4*)(x + ((size_t)(b * DIM + c)) * NPOS + n0 + colb);
    short4v o;
    o.x = f2b((v.x - mean) * rstd * ga + be);
    o.y = f2b((v.y - mean) * rstd * ga + be);
    o.z = f2b((v.z - mean) * rstd * ga + be);
    o.w = f2b((v.w - mean) * rstd * ga + be);
    *(short4v*)&lt[row * 72 + colb] = o;
  }
  __syncthreads();
  #pragma unroll
  for (int p = 0; p < 2; ++p) {
    int nr = (t >> 3) + p * 32;
    int ch = t & 7;
    short8 o;
    #pragma unroll
    for (int j = 0; j < 8; ++j) o[j] = lt[(ch * 8 + j) * 72 + nr];
    *(short8*)(ht + ((size_t)(b * NPOS + n0 + nr)) * DIM + c0 + ch * 8) = o;
  }
}

// ---------------- gemm_bt: C[M,N] = A[M,K] * B[N,K]^T, K=256, 128x128 tile ----------------
template <int MODE>
__launch_bounds__(256, 2)
__global__ void k_gemm(const short* __restrict__ A, const short* __restrict__ Bm,
                       const float* __restrict__ bias,
                       short* __restrict__ qb, short* __restrict__ kb, short* __restrict__ vtb,
                       const float* __restrict__ resid, float* __restrict__ outf) {
  const int K = 256;
  int b = blockIdx.z;
  int m0 = blockIdx.x * 128, n0 = blockIdx.y * 128;
  const short* Ap = (MODE == 0) ? A + (size_t)b * NPOS * K : A;
  const short* Bp = (MODE == 0) ? Bm : Bm + (size_t)b * NPOS * K;

  __shared__ short As[128 * 64], Bs[128 * 64];
  int t = threadIdx.x;
  int lane = t & 63, wid = t >> 6;
  int wm = wid >> 1, wn = wid & 1;
  f32x4 acc[4][4] = {};

  for (int kt = 0; kt < 4; ++kt) {
    int k0 = kt * 64;
    short8 av[4], bv[4];
    #pragma unroll
    for (int p = 0; p < 4; ++p) {
      int ci = t + p * 256;
      int row = ci >> 3, ch = ci & 7;
      av[p] = *(const short8*)(Ap + (size_t)(m0 + row) * K + k0 + ch * 8);
      bv[p] = *(const short8*)(Bp + (size_t)(n0 + row) * K + k0 + ch * 8);
    }
    __syncthreads();
    #pragma unroll
    for (int p = 0; p < 4; ++p) {
      int ci = t + p * 256;
      int row = ci >> 3, ch = ci & 7;
      int off = (row * 128 + ch * 16) ^ ((row & 7) << 4);
      *(short8*)((char*)As + off) = av[p];
      *(short8*)((char*)Bs + off) = bv[p];
    }
    __syncthreads();
    #pragma unroll
    for (int ks = 0; ks < 2; ++ks) {
      short8 af[4], bf[4];
      int inner = ks * 64 + (lane >> 4) * 16;
      #pragma unroll
      for (int mi = 0; mi < 4; ++mi) {
        int row = wm * 64 + mi * 16 + (lane & 15);
        af[mi] = *(short8*)((char*)As + ((row * 128 + inner) ^ ((row & 7) << 4)));
      }
      #pragma unroll
      for (int ni = 0; ni < 4; ++ni) {
        int row = wn * 64 + ni * 16 + (lane & 15);
        bf[ni] = *(short8*)((char*)Bs + ((row * 128 + inner) ^ ((row & 7) << 4)));
      }
      #pragma unroll
      for (int mi = 0; mi < 4; ++mi)
        #pragma unroll
        for (int ni = 0; ni < 4; ++ni)
          acc[mi][ni] = __builtin_amdgcn_mfma_f32_16x16x32_bf16(af[mi], bf[ni], acc[mi][ni], 0, 0, 0);
    }
  }

  #pragma unroll
  for (int mi = 0; mi < 4; ++mi)
    #pragma unroll
    for (int ni = 0; ni < 4; ++ni) {
      int gcol = n0 + wn * 64 + ni * 16 + (lane & 15);
      #pragma unroll
      for (int r = 0; r < 4; ++r) {
        int grow = m0 + wm * 64 + mi * 16 + (lane >> 4) * 4 + r;
        if (MODE == 0) {
          float v = acc[mi][ni][r] + bias[gcol];
          short h = f2b(v);
          if (gcol < 256)       qb[((size_t)b * NPOS + grow) * DIM + gcol] = h;
          else if (gcol < 512)  kb[((size_t)b * NPOS + grow) * DIM + gcol - 256] = h;
          else                  vtb[((size_t)b * DIM + gcol - 512) * NPOS + grow] = h;
        } else {
          float v = acc[mi][ni][r] + bias[grow];
          size_t idx = ((size_t)b * DIM + grow) * NPOS + gcol;
          outf[idx] = v + resid[idx];
        }
      }
    }
}

// ---- flash v13 = v6b core with V direct-to-register (one-iter prefetch, ping-pong vA/vB).
// K: gl16 LDS dbuf (unchanged). V: per-lane 16B global loads of the exact A-fragment,
// issued at iter top for it+1, consumed next iter (latency covered by full iteration).
// 32x32x16 MFMA, in-register P (cvt_pk + permlane32_swap), KVBLK=32.
// 4 waves = 2 q-pairs(32 rows) x 2 kv-halves(2048), 1 barrier/iter.
// LDS (101376): K[buf][h]@buf*32768+h*16384 (32x512B rows, swz ^((row&7)<<4)) in [0,64K);
// epilogue aliases: sc32@0 (257w stride), sc16@66560 (258 stride), lm@100352.
__launch_bounds__(256, 1)
__global__ void k_flash(const short* __restrict__ qb, const short* __restrict__ kb,
                        const short* __restrict__ vtb, short* __restrict__ ob) {
  __shared__ __align__(16) char smem[101376];

  int i = blockIdx.x;
  int xcd = i & 7, slot = i >> 3;
  int b = xcd >> 1;
  int bx = slot * 2 + (xcd & 1);   // 0..63
  int q0 = bx * 64;

  int t = threadIdx.x, lane = t & 63, wid = t >> 6;
  int q = lane & 31, hi = lane >> 5;
  int qs = wid & 1, h = wid >> 1;

  const short* kbB = kb + (size_t)b * NPOS * DIM;
  const short* vbB = vtb + (size_t)b * DIM * NPOS;

  // ---- Q fragments (B-operand, 32x32x16: row=lane&31, k=hi*8+[0..7]), pre-scaled 1/16 ----
  short8 qf[16];
  {
    int qrow = q0 + qs * 32 + q;
    const short* qp = qb + ((size_t)b * NPOS + qrow) * DIM + hi * 8;
    #pragma unroll
    for (int s = 0; s < 16; ++s) {
      short8 v = *(const short8*)(qp + s * 16);
      #pragma unroll
      for (int j = 0; j < 8; ++j) {
        float f = __uint_as_float(((unsigned)(unsigned short)v[j]) << 16) * 0.0625f;
        v[j] = f2b(f);
      }
      qf[s] = v;
    }
  }

  // ---- K staging source pointers (pre-swizzled global columns; LDS dest linear) ----
  unsigned su = h * 16384u + qs * 8192u;
  const short* srcK[8];
  {
    int l5 = lane >> 5, l31 = lane & 31;
    #pragma unroll
    for (int j = 0; j < 8; ++j) {
      int r = qs * 16 + j * 2 + l5;
      int colb = (l31 * 16) ^ ((r & 7) << 4);
      srcK[j] = kbB + (size_t)(h * 2048 + r) * DIM + (colb >> 1);
    }
  }

  // ---- V per-lane fragment base: V[d = dt*32+q][kv0 + hi*8 + (0..7)], h-half offset ----
  const short* vbase = vbB + (size_t)q * NPOS + h * 2048 + hi * 8;

  f32x16 oacc[8] = {};
  float m = -1e30f, l = 0.f;
  short8 vA[16], vB[16];

  const int NIT = 64;
  int buf = 0;
  // prologue: K tile 0 -> LDS buf0; V tile 0 -> vA
  #pragma unroll
  for (int j = 0; j < 8; ++j) gl16(srcK[j], smem + su + j * 1024u);
  #pragma unroll
  for (int dt = 0; dt < 8; ++dt) {
    vA[2 * dt]     = *(const short8*)(vbase + (size_t)dt * 32 * NPOS);
    vA[2 * dt + 1] = *(const short8*)(vbase + (size_t)dt * 32 * NPOS + 16);
  }
  __syncthreads();

  const unsigned kx = (unsigned)((q & 7) << 4);

#define FITER(IT, VC, VN)                                                          \
  {                                                                                \
    if ((IT) + 1 < NIT) {                                                          \
      size_t ko = (size_t)((IT) + 1) * 32 * DIM;                                   \
      unsigned nb = (unsigned)(buf ^ 1) * 32768u + su;                             \
      _Pragma("unroll")                                                            \
      for (int j = 0; j < 8; ++j) gl16(srcK[j] + ko, smem + nb + j * 1024u);       \
      const short* vb2 = vbase + ((IT) + 1) * 32;                                  \
      _Pragma("unroll")                                                            \
      for (int dt = 0; dt < 8; ++dt) {                                             \
        VN[2 * dt]     = *(const short8*)(vb2 + (size_t)dt * 32 * NPOS);           \
        VN[2 * dt + 1] = *(const short8*)(vb2 + (size_t)dt * 32 * NPOS + 16);      \
      }                                                                            \
    }                                                                              \
    const char* kl = smem + (unsigned)buf * 32768u + h * 16384u;                   \
    f32x16 sacc = {};                                                              \
    _Pragma("unroll")                                                              \
    for (int s = 0; s < 16; ++s) {                                                 \
      short8 kf = *(const short8*)(kl + q * 512u + ((s * 32u + hi * 16u) ^ kx));   \
      sacc = __builtin_amdgcn_mfma_f32_32x32x16_bf16(kf, qf[s], sacc, 0, 0, 0);    \
    }                                                                              \
    float mx = sacc[0];                                                            \
    _Pragma("unroll")                                                              \
    for (int r = 1; r < 16; ++r) mx = fmaxf(mx, sacc[r]);                          \
    mx = fmaxf(mx, __shfl_xor(mx, 32, 64));                                        \
    if (!__all(mx <= m + 8.f)) {                                                   \
      float mn = fmaxf(m, mx);                                                     \
      float al = __expf(m - mn);                                                   \
      m = mn; l *= al;                                                             \
      _Pragma("unroll")                                                            \
      for (int dt = 0; dt < 8; ++dt)                                               \
        _Pragma("unroll")                                                          \
        for (int r = 0; r < 16; ++r) oacc[dt][r] *= al;                            \
    }                                                                              \
    float p_[16];                                                                  \
    float ts = 0.f;                                                                \
    _Pragma("unroll")                                                              \
    for (int r = 0; r < 16; ++r) { p_[r] = __expf(sacc[r] - m); ts += p_[r]; }     \
    ts += __shfl_xor(ts, 32, 64);                                                  \
    l += ts;                                                                       \
    unsigned w0, w1, w2, w3, w4, w5, w6, w7;                                       \
    asm("v_cvt_pk_bf16_f32 %0, %1, %2" : "=v"(w0) : "v"(p_[0]),  "v"(p_[1]));      \
    asm("v_cvt_pk_bf16_f32 %0, %1, %2" : "=v"(w1) : "v"(p_[2]),  "v"(p_[3]));      \
    asm("v_cvt_pk_bf16_f32 %0, %1, %2" : "=v"(w2) : "v"(p_[4]),  "v"(p_[5]));      \
    asm("v_cvt_pk_bf16_f32 %0, %1, %2" : "=v"(w3) : "v"(p_[6]),  "v"(p_[7]));      \
    asm("v_cvt_pk_bf16_f32 %0, %1, %2" : "=v"(w4) : "v"(p_[8]),  "v"(p_[9]));      \
    asm("v_cvt_pk_bf16_f32 %0, %1, %2" : "=v"(w5) : "v"(p_[10]), "v"(p_[11]));     \
    asm("v_cvt_pk_bf16_f32 %0, %1, %2" : "=v"(w6) : "v"(p_[12]), "v"(p_[13]));     \
    asm("v_cvt_pk_bf16_f32 %0, %1, %2" : "=v"(w7) : "v"(p_[14]), "v"(p_[15]));     \
    asm("v_permlane32_swap_b32 %0, %1" : "+v"(w0), "+v"(w2));                      \
    asm("v_permlane32_swap_b32 %0, %1" : "+v"(w1), "+v"(w3));                      \
    asm("v_permlane32_swap_b32 %0, %1" : "+v"(w4), "+v"(w6));                      \
    asm("v_permlane32_swap_b32 %0, %1" : "+v"(w5), "+v"(w7));                      \
    short8 pf0 = __builtin_bit_cast(short8, (u32x4){w0, w1, w2, w3});              \
    short8 pf1 = __builtin_bit_cast(short8, (u32x4){w4, w5, w6, w7});              \
    _Pragma("unroll")                                                              \
    for (int dt = 0; dt < 8; ++dt) {                                               \
      oacc[dt] = __builtin_amdgcn_mfma_f32_32x32x16_bf16(VC[2*dt],   pf0, oacc[dt], 0, 0, 0); \
      oacc[dt] = __builtin_amdgcn_mfma_f32_32x32x16_bf16(VC[2*dt+1], pf1, oacc[dt], 0, 0, 0); \
    }                                                                              \
    __syncthreads();                                                               \
    buf ^= 1;                                                                      \
  }

  for (int it = 0; it < NIT; it += 2) {
    FITER(it, vA, vB)
    FITER(it + 1, vB, vA)
  }
#undef FITER

  // ---- combine the two kv-halves; everything per-lane (q-local) ----
  float* lmm = (float*)(smem + 100352);
  float* lml = lmm + 128;
  if (lane < 32) { lmm[(qs * 2 + h) * 32 + q] = m; lml[(qs * 2 + h) * 32 + q] = l; }
  __syncthreads();
  float mo = lmm[(qs * 2 + (h ^ 1)) * 32 + q];
  float lo = lml[(qs * 2 + (h ^ 1)) * 32 + q];
  float M = fmaxf(m, mo);
  float al = __expf(m - M);
  float Lf = l * al + lo * __expf(mo - M);
  float iL = 1.f / Lf;

  float* sc32 = (float*)smem;                // [qs][32 q][257w] f32
  short* sc16 = (short*)(smem + 66560);      // [qs][32 q][258]  bf16
  if (h == 0) {
    #pragma unroll
    for (int dt = 0; dt < 8; ++dt)
      #pragma unroll
      for (int r = 0; r < 16; ++r) {
        int d = dt * 32 + (r & 3) + 8 * (r >> 2) + 4 * hi;
        sc32[qs * 8224 + q * 257 + d] = oacc[dt][r] * al;
      }
  }
  __syncthreads();
  if (h == 1) {
    #pragma unroll
    for (int dt = 0; dt < 8; ++dt)
      #pragma unroll
      for (int r = 0; r < 16; ++r) {
        int d = dt * 32 + (r & 3) + 8 * (r >> 2) + 4 * hi;
        float v = (sc32[qs * 8224 + q * 257 + d] + oacc[dt][r] * al) * iL;
        sc16[qs * 8256 + q * 258 + d] = f2b(v);
      }
  }
  __syncthreads();
  // cooperative coalesced copy to global
  {
    int row = t >> 2;                        // 0..63 = qs*32+q
    const short* src = sc16 + (row >> 5) * 8256 + (row & 31) * 258 + (t & 3) * 64;
    short* dst = ob + ((size_t)b * NPOS + q0 + row) * DIM + (t & 3) * 64;
    #pragma unroll
    for (int j = 0; j < 8; ++j)
      *(short8*)(dst + j * 8) = *(const short8*)(src + j * 8);
  }
}

extern "C" void kernel_launch(void* const* d_in, const int* in_sizes, int n_in,
                              void* d_out, int out_size, void* d_ws, size_t ws_size,
                              hipStream_t stream) {
  const float* x     = (const float*)d_in[0];
  const float* gamma = (const float*)d_in[1];
  const float* beta  = (const float*)d_in[2];
  const float* wqkv  = (const float*)d_in[3];
  const float* bqkv  = (const float*)d_in[4];
  const float* wproj = (const float*)d_in[5];
  const float* bproj = (const float*)d_in[6];
  float* out = (float*)d_out;

  char* ws = (char*)d_ws;
  float* stats = (float*)ws;
  short* wqb = (short*)(ws + 1024);
  short* wpb = (short*)(ws + 1024 + 393216);
  size_t off = 1024 + 393216 + 131072;
  const size_t SZ = (size_t)NB * NPOS * DIM * sizeof(short);  // 8 MB
  short* ht   = (short*)(ws + off); off += SZ;
  short* qbuf = (short*)(ws + off); off += SZ;
  short* kbuf = (short*)(ws + off); off += SZ;
  short* vtb  = (short*)(ws + off); off += SZ;
  short* obuf = ht;  // h_t dead after QKV gemm; reuse for attention output

  k_convert_w<<<768, 256, 0, stream>>>(wqkv, wproj, wqb, wpb);
  k_gn_stats<<<128, 256, 0, stream>>>(x, stats);
  k_gn_apply<<<dim3(4, 64, NB), 256, 0, stream>>>(x, stats, gamma, beta, ht);
  k_gemm<0><<<dim3(32, 6, NB), 256, 0, stream>>>(ht, wqb, bqkv, qbuf, kbuf, vtb, nullptr, nullptr);
  k_flash<<<dim3(256), 256, 0, stream>>>(qbuf, kbuf, vtb, obuf);
  k_gemm<1><<<dim3(2, 32, NB), 256, 0, stream>>>(wpb, obuf, bproj, nullptr, nullptr, nullptr, x, out);
}

// Round 14
// 176.117 us; speedup vs baseline: 1.5142x; 1.5142x over previous
//
#include <hip/hip_runtime.h>
#include <stdint.h>

#define DIM 256
#define NPOS 4096
#define NB 4
#define GROUPS 32

typedef __attribute__((ext_vector_type(8))) short short8;
typedef __attribute__((ext_vector_type(4))) short short4v;
typedef __attribute__((ext_vector_type(4))) float f32x4;
typedef __attribute__((ext_vector_type(16))) float f32x16;
typedef __attribute__((ext_vector_type(2))) unsigned int u32x2;
typedef __attribute__((ext_vector_type(4))) unsigned int u32x4;

__device__ __forceinline__ short f2b(float f) {
  unsigned u = __float_as_uint(f);
  unsigned r = (u + 0x7fffu + ((u >> 16) & 1u)) >> 16;
  return (short)r;
}

__device__ __forceinline__ void gl16(const short* g, char* lds) {
  __builtin_amdgcn_global_load_lds((const __attribute__((address_space(1))) void*)g,
                                   (__attribute__((address_space(3))) void*)lds, 16, 0, 0);
}

// ---------------- weight conversion (f32 -> bf16) ----------------
__global__ void k_convert_w(const float* __restrict__ wq, const float* __restrict__ wp,
                            short* __restrict__ wqb, short* __restrict__ wpb) {
  int i = blockIdx.x * 256 + threadIdx.x;
  if (i < 768 * 256) wqb[i] = f2b(wq[i]);
  if (i < 256 * 256) wpb[i] = f2b(wp[i]);
}

// ---------------- GroupNorm stats: one block per (b,g) ----------------
__global__ void k_gn_stats(const float* __restrict__ x, float* __restrict__ stats) {
  int bg = blockIdx.x;
  const float4* b4 = (const float4*)(x + (size_t)bg * 8 * NPOS);
  float s = 0.f, ss = 0.f;
  for (int i = threadIdx.x; i < 8192; i += 256) {
    float4 v = b4[i];
    s  += v.x + v.y + v.z + v.w;
    ss += v.x * v.x + v.y * v.y + v.z * v.z + v.w * v.w;
  }
  #pragma unroll
  for (int m = 1; m < 64; m <<= 1) { s += __shfl_xor(s, m, 64); ss += __shfl_xor(ss, m, 64); }
  __shared__ float red[8];
  int wid = threadIdx.x >> 6;
  if ((threadIdx.x & 63) == 0) { red[wid * 2] = s; red[wid * 2 + 1] = ss; }
  __syncthreads();
  if (threadIdx.x == 0) {
    float S = red[0] + red[2] + red[4] + red[6];
    float SS = red[1] + red[3] + red[5] + red[7];
    float mean = S / 32768.f;
    float var = SS / 32768.f - mean * mean;
    stats[bg * 2] = mean;
    stats[bg * 2 + 1] = rsqrtf(var + 1e-6f);
  }
}

// ------------- GroupNorm apply + transpose: x(B,C,N) f32 -> h_t(B,N,C) bf16 -------------
__global__ void k_gn_apply(const float* __restrict__ x, const float* __restrict__ stats,
                           const float* __restrict__ gamma, const float* __restrict__ beta,
                           short* __restrict__ ht) {
  int ct = blockIdx.x, nt = blockIdx.y, b = blockIdx.z;
  int c0 = ct * 64, n0 = nt * 64;
  __shared__ short lt[64 * 72];
  int t = threadIdx.x;
  #pragma unroll
  for (int p = 0; p < 4; ++p) {
    int row = (t >> 4) + p * 16;
    int colb = (t & 15) * 4;
    int c = c0 + row;
    float mean = stats[(b * GROUPS + (c >> 3)) * 2];
    float rstd = stats[(b * GROUPS + (c >> 3)) * 2 + 1];
    float ga = gamma[c], be = beta[c];
    float4 v = *(const float4*)(x + ((size_t)(b * DIM + c)) * NPOS + n0 + colb);
    short4v o;
    o.x = f2b((v.x - mean) * rstd * ga + be);
    o.y = f2b((v.y - mean) * rstd * ga + be);
    o.z = f2b((v.z - mean) * rstd * ga + be);
    o.w = f2b((v.w - mean) * rstd * ga + be);
    *(short4v*)&lt[row * 72 + colb] = o;
  }
  __syncthreads();
  #pragma unroll
  for (int p = 0; p < 2; ++p) {
    int nr = (t >> 3) + p * 32;
    int ch = t & 7;
    short8 o;
    #pragma unroll
    for (int j = 0; j < 8; ++j) o[j] = lt[(ch * 8 + j) * 72 + nr];
    *(short8*)(ht + ((size_t)(b * NPOS + n0 + nr)) * DIM + c0 + ch * 8) = o;
  }
}

// ---------------- gemm_bt: C[M,N] = A[M,K] * B[N,K]^T, K=256, 128x128 tile ----------------
template <int MODE>
__launch_bounds__(256, 2)
__global__ void k_gemm(const short* __restrict__ A, const short* __restrict__ Bm,
                       const float* __restrict__ bias,
                       short* __restrict__ qb, short* __restrict__ kb, short* __restrict__ vtb,
                       const float* __restrict__ resid, float* __restrict__ outf) {
  const int K = 256;
  int b = blockIdx.z;
  int m0 = blockIdx.x * 128, n0 = blockIdx.y * 128;
  const short* Ap = (MODE == 0) ? A + (size_t)b * NPOS * K : A;
  const short* Bp = (MODE == 0) ? Bm : Bm + (size_t)b * NPOS * K;

  __shared__ short As[128 * 64], Bs[128 * 64];
  int t = threadIdx.x;
  int lane = t & 63, wid = t >> 6;
  int wm = wid >> 1, wn = wid & 1;
  f32x4 acc[4][4] = {};

  for (int kt = 0; kt < 4; ++kt) {
    int k0 = kt * 64;
    short8 av[4], bv[4];
    #pragma unroll
    for (int p = 0; p < 4; ++p) {
      int ci = t + p * 256;
      int row = ci >> 3, ch = ci & 7;
      av[p] = *(const short8*)(Ap + (size_t)(m0 + row) * K + k0 + ch * 8);
      bv[p] = *(const short8*)(Bp + (size_t)(n0 + row) * K + k0 + ch * 8);
    }
    __syncthreads();
    #pragma unroll
    for (int p = 0; p < 4; ++p) {
      int ci = t + p * 256;
      int row = ci >> 3, ch = ci & 7;
      int off = (row * 128 + ch * 16) ^ ((row & 7) << 4);
      *(short8*)((char*)As + off) = av[p];
      *(short8*)((char*)Bs + off) = bv[p];
    }
    __syncthreads();
    #pragma unroll
    for (int ks = 0; ks < 2; ++ks) {
      short8 af[4], bf[4];
      int inner = ks * 64 + (lane >> 4) * 16;
      #pragma unroll
      for (int mi = 0; mi < 4; ++mi) {
        int row = wm * 64 + mi * 16 + (lane & 15);
        af[mi] = *(short8*)((char*)As + ((row * 128 + inner) ^ ((row & 7) << 4)));
      }
      #pragma unroll
      for (int ni = 0; ni < 4; ++ni) {
        int row = wn * 64 + ni * 16 + (lane & 15);
        bf[ni] = *(short8*)((char*)Bs + ((row * 128 + inner) ^ ((row & 7) << 4)));
      }
      #pragma unroll
      for (int mi = 0; mi < 4; ++mi)
        #pragma unroll
        for (int ni = 0; ni < 4; ++ni)
          acc[mi][ni] = __builtin_amdgcn_mfma_f32_16x16x32_bf16(af[mi], bf[ni], acc[mi][ni], 0, 0, 0);
    }
  }

  #pragma unroll
  for (int mi = 0; mi < 4; ++mi)
    #pragma unroll
    for (int ni = 0; ni < 4; ++ni) {
      int gcol = n0 + wn * 64 + ni * 16 + (lane & 15);
      #pragma unroll
      for (int r = 0; r < 4; ++r) {
        int grow = m0 + wm * 64 + mi * 16 + (lane >> 4) * 4 + r;
        if (MODE == 0) {
          float v = acc[mi][ni][r] + bias[gcol];
          short h = f2b(v);
          if (gcol < 256)       qb[((size_t)b * NPOS + grow) * DIM + gcol] = h;
          else if (gcol < 512)  kb[((size_t)b * NPOS + grow) * DIM + gcol - 256] = h;
          else                  vtb[((size_t)b * DIM + gcol - 512) * NPOS + grow] = h;
        } else {
          float v = acc[mi][ni][r] + bias[grow];
          size_t idx = ((size_t)b * DIM + grow) * NPOS + gcol;
          outf[idx] = v + resid[idx];
        }
      }
    }
}

// ---- flash v6b (empirical best, rounds 8/12): 32x32x16 MFMA, in-register P
// (cvt_pk + permlane32_swap), KVBLK=32. 4 waves = 2 q-pairs(32 rows) x 2 kv-halves(2048).
// gl16 dbuf staging, 1 barrier/iter.
// S^T = mfma(K, Q): lane owns q=lane&31, 16 kv in regs -> softmax fully in-lane.
// PV: O = mfma(V^T-frag, P-frag): lane owns q, regs = d. No P LDS at all.
// permlane32_swap(first, second): first.upper32 <-> second.lower32. With
// w_j = pack(p[2j],p[2j+1]) (reg r ~ kv=(r&3)+8*(r>>2)+4*hi): swap(w0,w2) makes
// w0 = {hi0:(kv0,1), hi1:(kv8,9)} = pf0.word0 and w2 = {(4,5),(12,13)} = pf0.word2.
// LDS (131072): K[buf][h]@buf*32768+h*16384 (32x512B rows, swz ^((row&7)<<4));
//   V[buf][h]@65536+buf*32768+h*16384 ([256d][32kv] 64B rows, swz ^((row&6)<<3)).
// Epilogue aliases: sc32@0 (257w stride), sc16@66560 (258 stride), lm@100352.
__launch_bounds__(256, 1)
__global__ void k_flash(const short* __restrict__ qb, const short* __restrict__ kb,
                        const short* __restrict__ vtb, short* __restrict__ ob) {
  __shared__ __align__(16) char smem[131072];

  int i = blockIdx.x;
  int xcd = i & 7, slot = i >> 3;
  int b = xcd >> 1;
  int bx = slot * 2 + (xcd & 1);   // 0..63
  int q0 = bx * 64;

  int t = threadIdx.x, lane = t & 63, wid = t >> 6;
  int q = lane & 31, hi = lane >> 5;
  int qs = wid & 1, h = wid >> 1;

  const short* kbB = kb + (size_t)b * NPOS * DIM;
  const short* vbB = vtb + (size_t)b * DIM * NPOS;

  // ---- Q fragments (B-operand, 32x32x16: row=lane&31, k=hi*8+[0..7]), pre-scaled 1/16 ----
  short8 qf[16];
  {
    int qrow = q0 + qs * 32 + q;
    const short* qp = qb + ((size_t)b * NPOS + qrow) * DIM + hi * 8;
    #pragma unroll
    for (int s = 0; s < 16; ++s) {
      short8 v = *(const short8*)(qp + s * 16);
      #pragma unroll
      for (int j = 0; j < 8; ++j) {
        float f = __uint_as_float(((unsigned)(unsigned short)v[j]) << 16) * 0.0625f;
        v[j] = f2b(f);
      }
      qf[s] = v;
    }
  }

  // ---- staging source pointers (pre-swizzled global columns; LDS dest linear) ----
  unsigned su = h * 16384u + qs * 8192u;
  const short* srcK[8];
  const short* srcV[8];
  {
    int l5 = lane >> 5, l31 = lane & 31;
    #pragma unroll
    for (int j = 0; j < 8; ++j) {
      int r = qs * 16 + j * 2 + l5;
      int colb = (l31 * 16) ^ ((r & 7) << 4);
      srcK[j] = kbB + (size_t)(h * 2048 + r) * DIM + (colb >> 1);
      int vr = qs * 128 + j * 16 + (lane >> 2);
      int vcol = ((lane & 3) * 16) ^ ((vr & 6) << 3);
      srcV[j] = vbB + (size_t)vr * NPOS + h * 2048 + (vcol >> 1);
    }
  }

  f32x16 oacc[8] = {};
  float m = -1e30f, l = 0.f;

  const int NIT = 64;
  int buf = 0;
  // prologue: stage tile 0 into buf0
  #pragma unroll
  for (int j = 0; j < 8; ++j) {
    gl16(srcK[j], smem + su + j * 1024u);
    gl16(srcV[j], smem + 65536u + su + j * 1024u);
  }
  __syncthreads();

  const unsigned kx = (unsigned)((q & 7) << 4);
  const unsigned vx = (unsigned)((q & 6) << 3);

  for (int it = 0; it < NIT; ++it) {
    // stage next tile into buf^1 (latency hides under this iter's compute)
    if (it + 1 < NIT) {
      size_t ko = (size_t)(it + 1) * 32 * DIM;
      int vo = (it + 1) * 32;
      unsigned nb = (unsigned)(buf ^ 1) * 32768u + su;
      #pragma unroll
      for (int j = 0; j < 8; ++j) {
        gl16(srcK[j] + ko, smem + nb + j * 1024u);
        gl16(srcV[j] + vo, smem + 65536u + nb + j * 1024u);
      }
    }

    // ---- QK^T (swapped): one 32x32 S^T tile, scale folded into Q ----
    const char* kl = smem + (unsigned)buf * 32768u + h * 16384u;
    const char* vl = smem + 65536u + (unsigned)buf * 32768u + h * 16384u;
    f32x16 sacc = {};
    #pragma unroll
    for (int s = 0; s < 16; ++s) {
      short8 kf = *(const short8*)(kl + q * 512u + ((s * 32u + hi * 16u) ^ kx));
      sacc = __builtin_amdgcn_mfma_f32_32x32x16_bf16(kf, qf[s], sacc, 0, 0, 0);
    }

    // ---- online softmax fully in-lane (lane owns q; 16 kv here + 16 at partner) ----
    float mx = sacc[0];
    #pragma unroll
    for (int r = 1; r < 16; ++r) mx = fmaxf(mx, sacc[r]);
    mx = fmaxf(mx, __shfl_xor(mx, 32, 64));
    if (!__all(mx <= m + 8.f)) {
      float mn = fmaxf(m, mx);
      float al = __expf(m - mn);
      m = mn; l *= al;
      #pragma unroll
      for (int dt = 0; dt < 8; ++dt)
        #pragma unroll
        for (int r = 0; r < 16; ++r) oacc[dt][r] *= al;
    }
    float p_[16];
    float ts = 0.f;
    #pragma unroll
    for (int r = 0; r < 16; ++r) { p_[r] = __expf(sacc[r] - m); ts += p_[r]; }
    ts += __shfl_xor(ts, 32, 64);
    l += ts;

    // ---- P -> bf16 A-frag entirely in registers ----
    unsigned w0, w1, w2, w3, w4, w5, w6, w7;
    asm("v_cvt_pk_bf16_f32 %0, %1, %2" : "=v"(w0) : "v"(p_[0]),  "v"(p_[1]));
    asm("v_cvt_pk_bf16_f32 %0, %1, %2" : "=v"(w1) : "v"(p_[2]),  "v"(p_[3]));
    asm("v_cvt_pk_bf16_f32 %0, %1, %2" : "=v"(w2) : "v"(p_[4]),  "v"(p_[5]));
    asm("v_cvt_pk_bf16_f32 %0, %1, %2" : "=v"(w3) : "v"(p_[6]),  "v"(p_[7]));
    asm("v_cvt_pk_bf16_f32 %0, %1, %2" : "=v"(w4) : "v"(p_[8]),  "v"(p_[9]));
    asm("v_cvt_pk_bf16_f32 %0, %1, %2" : "=v"(w5) : "v"(p_[10]), "v"(p_[11]));
    asm("v_cvt_pk_bf16_f32 %0, %1, %2" : "=v"(w6) : "v"(p_[12]), "v"(p_[13]));
    asm("v_cvt_pk_bf16_f32 %0, %1, %2" : "=v"(w7) : "v"(p_[14]), "v"(p_[15]));
    asm("v_permlane32_swap_b32 %0, %1" : "+v"(w0), "+v"(w2));
    asm("v_permlane32_swap_b32 %0, %1" : "+v"(w1), "+v"(w3));
    asm("v_permlane32_swap_b32 %0, %1" : "+v"(w4), "+v"(w6));
    asm("v_permlane32_swap_b32 %0, %1" : "+v"(w5), "+v"(w7));
    short8 pf0 = __builtin_bit_cast(short8, (u32x4){w0, w1, w2, w3});  // kv 0..15
    short8 pf1 = __builtin_bit_cast(short8, (u32x4){w4, w5, w6, w7});  // kv 16..31

    // ---- PV: oacc[dt] += mfma(V^T-frag(d rows), P-frag(q rows)) ----
    #pragma unroll
    for (int dt = 0; dt < 8; ++dt) {
      unsigned vrow = (dt * 32u + q) * 64u;
      short8 vf0 = *(const short8*)(vl + vrow + ((hi * 16u) ^ vx));
      short8 vf1 = *(const short8*)(vl + vrow + ((32u + hi * 16u) ^ vx));
      oacc[dt] = __builtin_amdgcn_mfma_f32_32x32x16_bf16(vf0, pf0, oacc[dt], 0, 0, 0);
      oacc[dt] = __builtin_amdgcn_mfma_f32_32x32x16_bf16(vf1, pf1, oacc[dt], 0, 0, 0);
    }
    __syncthreads();   // next tile staged & visible; all reads of buf done
    buf ^= 1;
  }

  // ---- combine the two kv-halves; everything per-lane (q-local) ----
  float* lmm = (float*)(smem + 100352);
  float* lml = lmm + 128;
  if (lane < 32) { lmm[(qs * 2 + h) * 32 + q] = m; lml[(qs * 2 + h) * 32 + q] = l; }
  __syncthreads();
  float mo = lmm[(qs * 2 + (h ^ 1)) * 32 + q];
  float lo = lml[(qs * 2 + (h ^ 1)) * 32 + q];
  float M = fmaxf(m, mo);
  float al = __expf(m - M);
  float Lf = l * al + lo * __expf(mo - M);
  float iL = 1.f / Lf;

  float* sc32 = (float*)smem;                // [qs][32 q][257w] f32
  short* sc16 = (short*)(smem + 66560);      // [qs][32 q][258]  bf16
  if (h == 0) {
    #pragma unroll
    for (int dt = 0; dt < 8; ++dt)
      #pragma unroll
      for (int r = 0; r < 16; ++r) {
        int d = dt * 32 + (r & 3) + 8 * (r >> 2) + 4 * hi;
        sc32[qs * 8224 + q * 257 + d] = oacc[dt][r] * al;
      }
  }
  __syncthreads();
  if (h == 1) {
    #pragma unroll
    for (int dt = 0; dt < 8; ++dt)
      #pragma unroll
      for (int r = 0; r < 16; ++r) {
        int d = dt * 32 + (r & 3) + 8 * (r >> 2) + 4 * hi;
        float v = (sc32[qs * 8224 + q * 257 + d] + oacc[dt][r] * al) * iL;
        sc16[qs * 8256 + q * 258 + d] = f2b(v);
      }
  }
  __syncthreads();
  // cooperative coalesced copy to global
  {
    int row = t >> 2;                        // 0..63 = qs*32+q
    const short* src = sc16 + (row >> 5) * 8256 + (row & 31) * 258 + (t & 3) * 64;
    short* dst = ob + ((size_t)b * NPOS + q0 + row) * DIM + (t & 3) * 64;
    #pragma unroll
    for (int j = 0; j < 8; ++j)
      *(short8*)(dst + j * 8) = *(const short8*)(src + j * 8);
  }
}

extern "C" void kernel_launch(void* const* d_in, const int* in_sizes, int n_in,
                              void* d_out, int out_size, void* d_ws, size_t ws_size,
                              hipStream_t stream) {
  const float* x     = (const float*)d_in[0];
  const float* gamma = (const float*)d_in[1];
  const float* beta  = (const float*)d_in[2];
  const float* wqkv  = (const float*)d_in[3];
  const float* bqkv  = (const float*)d_in[4];
  const float* wproj = (const float*)d_in[5];
  const float* bproj = (const float*)d_in[6];
  float* out = (float*)d_out;

  char* ws = (char*)d_ws;
  float* stats = (float*)ws;
  short* wqb = (short*)(ws + 1024);
  short* wpb = (short*)(ws + 1024 + 393216);
  size_t off = 1024 + 393216 + 131072;
  const size_t SZ = (size_t)NB * NPOS * DIM * sizeof(short);  // 8 MB
  short* ht   = (short*)(ws + off); off += SZ;
  short* qbuf = (short*)(ws + off); off += SZ;
  short* kbuf = (short*)(ws + off); off += SZ;
  short* vtb  = (short*)(ws + off); off += SZ;
  short* obuf = ht;  // h_t dead after QKV gemm; reuse for attention output

  k_convert_w<<<768, 256, 0, stream>>>(wqkv, wproj, wqb, wpb);
  k_gn_stats<<<128, 256, 0, stream>>>(x, stats);
  k_gn_apply<<<dim3(4, 64, NB), 256, 0, stream>>>(x, stats, gamma, beta, ht);
  k_gemm<0><<<dim3(32, 6, NB), 256, 0, stream>>>(ht, wqb, bqkv, qbuf, kbuf, vtb, nullptr, nullptr);
  k_flash<<<dim3(256), 256, 0, stream>>>(qbuf, kbuf, vtb, obuf);
  k_gemm<1><<<dim3(2, 32, NB), 256, 0, stream>>>(wpb, obuf, bproj, nullptr, nullptr, nullptr, x, out);
}

// Round 16
// 176.066 us; speedup vs baseline: 1.5146x; 1.0003x over previous
//
#include <hip/hip_runtime.h>
#include <stdint.h>

#define DIM 256
#define NPOS 4096
#define NB 4
#define GROUPS 32

typedef __attribute__((ext_vector_type(8))) short short8;
typedef __attribute__((ext_vector_type(4))) short short4v;
typedef __attribute__((ext_vector_type(4))) float f32x4;
typedef __attribute__((ext_vector_type(16))) float f32x16;
typedef __attribute__((ext_vector_type(2))) unsigned int u32x2;
typedef __attribute__((ext_vector_type(4))) unsigned int u32x4;

__device__ __forceinline__ short f2b(float f) {
  unsigned u = __float_as_uint(f);
  unsigned r = (u + 0x7fffu + ((u >> 16) & 1u)) >> 16;
  return (short)r;
}

__device__ __forceinline__ void gl16(const short* g, char* lds) {
  __builtin_amdgcn_global_load_lds((const __attribute__((address_space(1))) void*)g,
                                   (__attribute__((address_space(3))) void*)lds, 16, 0, 0);
}

// ---------------- weight conversion (f32 -> bf16) ----------------
__global__ void k_convert_w(const float* __restrict__ wq, const float* __restrict__ wp,
                            short* __restrict__ wqb, short* __restrict__ wpb) {
  int i = blockIdx.x * 256 + threadIdx.x;
  if (i < 768 * 256) wqb[i] = f2b(wq[i]);
  if (i < 256 * 256) wpb[i] = f2b(wp[i]);
}

// ---------------- GroupNorm stats: one block per (b,g) ----------------
__global__ void k_gn_stats(const float* __restrict__ x, float* __restrict__ stats) {
  int bg = blockIdx.x;
  const float4* b4 = (const float4*)(x + (size_t)bg * 8 * NPOS);
  float s = 0.f, ss = 0.f;
  for (int i = threadIdx.x; i < 8192; i += 256) {
    float4 v = b4[i];
    s  += v.x + v.y + v.z + v.w;
    ss += v.x * v.x + v.y * v.y + v.z * v.z + v.w * v.w;
  }
  #pragma unroll
  for (int m = 1; m < 64; m <<= 1) { s += __shfl_xor(s, m, 64); ss += __shfl_xor(ss, m, 64); }
  __shared__ float red[8];
  int wid = threadIdx.x >> 6;
  if ((threadIdx.x & 63) == 0) { red[wid * 2] = s; red[wid * 2 + 1] = ss; }
  __syncthreads();
  if (threadIdx.x == 0) {
    float S = red[0] + red[2] + red[4] + red[6];
    float SS = red[1] + red[3] + red[5] + red[7];
    float mean = S / 32768.f;
    float var = SS / 32768.f - mean * mean;
    stats[bg * 2] = mean;
    stats[bg * 2 + 1] = rsqrtf(var + 1e-6f);
  }
}

// ------------- GroupNorm apply + transpose: x(B,C,N) f32 -> h_t(B,N,C) bf16 -------------
__global__ void k_gn_apply(const float* __restrict__ x, const float* __restrict__ stats,
                           const float* __restrict__ gamma, const float* __restrict__ beta,
                           short* __restrict__ ht) {
  int ct = blockIdx.x, nt = blockIdx.y, b = blockIdx.z;
  int c0 = ct * 64, n0 = nt * 64;
  __shared__ short lt[64 * 72];
  int t = threadIdx.x;
  #pragma unroll
  for (int p = 0; p < 4; ++p) {
    int row = (t >> 4) + p * 16;
    int colb = (t & 15) * 4;
    int c = c0 + row;
    float mean = stats[(b * GROUPS + (c >> 3)) * 2];
    float rstd = stats[(b * GROUPS + (c >> 3)) * 2 + 1];
    float ga = gamma[c], be = beta[c];
    float4 v = *(const float4*)(x + ((size_t)(b * DIM + c)) * NPOS + n0 + colb);
    short4v o;
    o.x = f2b((v.x - mean) * rstd * ga + be);
    o.y = f2b((v.y - mean) * rstd * ga + be);
    o.z = f2b((v.z - mean) * rstd * ga + be);
    o.w = f2b((v.w - mean) * rstd * ga + be);
    *(short4v*)&lt[row * 72 + colb] = o;
  }
  __syncthreads();
  #pragma unroll
  for (int p = 0; p < 2; ++p) {
    int nr = (t >> 3) + p * 32;
    int ch = t & 7;
    short8 o;
    #pragma unroll
    for (int j = 0; j < 8; ++j) o[j] = lt[(ch * 8 + j) * 72 + nr];
    *(short8*)(ht + ((size_t)(b * NPOS + n0 + nr)) * DIM + c0 + ch * 8) = o;
  }
}

// ---------------- gemm_bt: C[M,N] = A[M,K] * B[N,K]^T, K=256, 128x128 tile ----------------
template <int MODE>
__launch_bounds__(256, 2)
__global__ void k_gemm(const short* __restrict__ A, const short* __restrict__ Bm,
                       const float* __restrict__ bias,
                       short* __restrict__ qb, short* __restrict__ kb, short* __restrict__ vtb,
                       const float* __restrict__ resid, float* __restrict__ outf) {
  const int K = 256;
  int b = blockIdx.z;
  int m0 = blockIdx.x * 128, n0 = blockIdx.y * 128;
  const short* Ap = (MODE == 0) ? A + (size_t)b * NPOS * K : A;
  const short* Bp = (MODE == 0) ? Bm : Bm + (size_t)b * NPOS * K;

  __shared__ short As[128 * 64], Bs[128 * 64];
  int t = threadIdx.x;
  int lane = t & 63, wid = t >> 6;
  int wm = wid >> 1, wn = wid & 1;
  f32x4 acc[4][4] = {};

  for (int kt = 0; kt < 4; ++kt) {
    int k0 = kt * 64;
    short8 av[4], bv[4];
    #pragma unroll
    for (int p = 0; p < 4; ++p) {
      int ci = t + p * 256;
      int row = ci >> 3, ch = ci & 7;
      av[p] = *(const short8*)(Ap + (size_t)(m0 + row) * K + k0 + ch * 8);
      bv[p] = *(const short8*)(Bp + (size_t)(n0 + row) * K + k0 + ch * 8);
    }
    __syncthreads();
    #pragma unroll
    for (int p = 0; p < 4; ++p) {
      int ci = t + p * 256;
      int row = ci >> 3, ch = ci & 7;
      int off = (row * 128 + ch * 16) ^ ((row & 7) << 4);
      *(short8*)((char*)As + off) = av[p];
      *(short8*)((char*)Bs + off) = bv[p];
    }
    __syncthreads();
    #pragma unroll
    for (int ks = 0; ks < 2; ++ks) {
      short8 af[4], bf[4];
      int inner = ks * 64 + (lane >> 4) * 16;
      #pragma unroll
      for (int mi = 0; mi < 4; ++mi) {
        int row = wm * 64 + mi * 16 + (lane & 15);
        af[mi] = *(short8*)((char*)As + ((row * 128 + inner) ^ ((row & 7) << 4)));
      }
      #pragma unroll
      for (int ni = 0; ni < 4; ++ni) {
        int row = wn * 64 + ni * 16 + (lane & 15);
        bf[ni] = *(short8*)((char*)Bs + ((row * 128 + inner) ^ ((row & 7) << 4)));
      }
      #pragma unroll
      for (int mi = 0; mi < 4; ++mi)
        #pragma unroll
        for (int ni = 0; ni < 4; ++ni)
          acc[mi][ni] = __builtin_amdgcn_mfma_f32_16x16x32_bf16(af[mi], bf[ni], acc[mi][ni], 0, 0, 0);
    }
  }

  #pragma unroll
  for (int mi = 0; mi < 4; ++mi)
    #pragma unroll
    for (int ni = 0; ni < 4; ++ni) {
      int gcol = n0 + wn * 64 + ni * 16 + (lane & 15);
      #pragma unroll
      for (int r = 0; r < 4; ++r) {
        int grow = m0 + wm * 64 + mi * 16 + (lane >> 4) * 4 + r;
        if (MODE == 0) {
          float v = acc[mi][ni][r] + bias[gcol];
          short h = f2b(v);
          if (gcol < 256)       qb[((size_t)b * NPOS + grow) * DIM + gcol] = h;
          else if (gcol < 512)  kb[((size_t)b * NPOS + grow) * DIM + gcol - 256] = h;
          else                  vtb[((size_t)b * DIM + gcol - 512) * NPOS + grow] = h;
        } else {
          float v = acc[mi][ni][r] + bias[grow];
          size_t idx = ((size_t)b * DIM + grow) * NPOS + gcol;
          outf[idx] = v + resid[idx];
        }
      }
    }
}

// ---- flash v6b (final): 32x32x16 MFMA, in-register P (cvt_pk + permlane32_swap),
// KVBLK=32. 4 waves = 2 q-pairs(32 rows) x 2 kv-halves(2048). gl16 dbuf staging, 1 barrier/iter.
// S^T = mfma(K, Q): lane owns q=lane&31, 16 kv in regs -> softmax fully in-lane.
// PV: O = mfma(V^T-frag, P-frag): lane owns q, regs = d. No P LDS at all.
// permlane32_swap(first, second): first.upper32 <-> second.lower32. With
// w_j = pack(p[2j],p[2j+1]) (reg r ~ kv=(r&3)+8*(r>>2)+4*hi): swap(w0,w2) makes
// w0 = {hi0:(kv0,1), hi1:(kv8,9)} = pf0.word0 and w2 = {(4,5),(12,13)} = pf0.word2.
// LDS (131072): K[buf][h]@buf*32768+h*16384 (32x512B rows, swz ^((row&7)<<4));
//   V[buf][h]@65536+buf*32768+h*16384 ([256d][32kv] 64B rows, swz ^((row&6)<<3)).
// Epilogue aliases: sc32@0 (257w stride), sc16@66560 (258 stride), lm@100352.
// Ceiling note: sync-structure-bound (MfmaUtil 21%, HBM 2.7%, 1 wave/SIMD). The
// counted-vmcnt restructure (round 15) raced; per m152 a new sync template needs
// multi-run race-screening beyond this session. All other axes isolated & measured.
__launch_bounds__(256, 1)
__global__ void k_flash(const short* __restrict__ qb, const short* __restrict__ kb,
                        const short* __restrict__ vtb, short* __restrict__ ob) {
  __shared__ __align__(16) char smem[131072];

  int i = blockIdx.x;
  int xcd = i & 7, slot = i >> 3;
  int b = xcd >> 1;
  int bx = slot * 2 + (xcd & 1);   // 0..63
  int q0 = bx * 64;

  int t = threadIdx.x, lane = t & 63, wid = t >> 6;
  int q = lane & 31, hi = lane >> 5;
  int qs = wid & 1, h = wid >> 1;

  const short* kbB = kb + (size_t)b * NPOS * DIM;
  const short* vbB = vtb + (size_t)b * DIM * NPOS;

  // ---- Q fragments (B-operand, 32x32x16: row=lane&31, k=hi*8+[0..7]), pre-scaled 1/16 ----
  short8 qf[16];
  {
    int qrow = q0 + qs * 32 + q;
    const short* qp = qb + ((size_t)b * NPOS + qrow) * DIM + hi * 8;
    #pragma unroll
    for (int s = 0; s < 16; ++s) {
      short8 v = *(const short8*)(qp + s * 16);
      #pragma unroll
      for (int j = 0; j < 8; ++j) {
        float f = __uint_as_float(((unsigned)(unsigned short)v[j]) << 16) * 0.0625f;
        v[j] = f2b(f);
      }
      qf[s] = v;
    }
  }

  // ---- staging source pointers (pre-swizzled global columns; LDS dest linear) ----
  unsigned su = h * 16384u + qs * 8192u;
  const short* srcK[8];
  const short* srcV[8];
  {
    int l5 = lane >> 5, l31 = lane & 31;
    #pragma unroll
    for (int j = 0; j < 8; ++j) {
      int r = qs * 16 + j * 2 + l5;
      int colb = (l31 * 16) ^ ((r & 7) << 4);
      srcK[j] = kbB + (size_t)(h * 2048 + r) * DIM + (colb >> 1);
      int vr = qs * 128 + j * 16 + (lane >> 2);
      int vcol = ((lane & 3) * 16) ^ ((vr & 6) << 3);
      srcV[j] = vbB + (size_t)vr * NPOS + h * 2048 + (vcol >> 1);
    }
  }

  f32x16 oacc[8] = {};
  float m = -1e30f, l = 0.f;

  const int NIT = 64;
  int buf = 0;
  // prologue: stage tile 0 into buf0
  #pragma unroll
  for (int j = 0; j < 8; ++j) {
    gl16(srcK[j], smem + su + j * 1024u);
    gl16(srcV[j], smem + 65536u + su + j * 1024u);
  }
  __syncthreads();

  const unsigned kx = (unsigned)((q & 7) << 4);
  const unsigned vx = (unsigned)((q & 6) << 3);

  for (int it = 0; it < NIT; ++it) {
    // stage next tile into buf^1 (latency hides under this iter's compute)
    if (it + 1 < NIT) {
      size_t ko = (size_t)(it + 1) * 32 * DIM;
      int vo = (it + 1) * 32;
      unsigned nb = (unsigned)(buf ^ 1) * 32768u + su;
      #pragma unroll
      for (int j = 0; j < 8; ++j) {
        gl16(srcK[j] + ko, smem + nb + j * 1024u);
        gl16(srcV[j] + vo, smem + 65536u + nb + j * 1024u);
      }
    }

    // ---- QK^T (swapped): one 32x32 S^T tile, scale folded into Q ----
    const char* kl = smem + (unsigned)buf * 32768u + h * 16384u;
    const char* vl = smem + 65536u + (unsigned)buf * 32768u + h * 16384u;
    f32x16 sacc = {};
    #pragma unroll
    for (int s = 0; s < 16; ++s) {
      short8 kf = *(const short8*)(kl + q * 512u + ((s * 32u + hi * 16u) ^ kx));
      sacc = __builtin_amdgcn_mfma_f32_32x32x16_bf16(kf, qf[s], sacc, 0, 0, 0);
    }

    // ---- online softmax fully in-lane (lane owns q; 16 kv here + 16 at partner) ----
    float mx = sacc[0];
    #pragma unroll
    for (int r = 1; r < 16; ++r) mx = fmaxf(mx, sacc[r]);
    mx = fmaxf(mx, __shfl_xor(mx, 32, 64));
    if (!__all(mx <= m + 8.f)) {
      float mn = fmaxf(m, mx);
      float al = __expf(m - mn);
      m = mn; l *= al;
      #pragma unroll
      for (int dt = 0; dt < 8; ++dt)
        #pragma unroll
        for (int r = 0; r < 16; ++r) oacc[dt][r] *= al;
    }
    float p_[16];
    float ts = 0.f;
    #pragma unroll
    for (int r = 0; r < 16; ++r) { p_[r] = __expf(sacc[r] - m); ts += p_[r]; }
    ts += __shfl_xor(ts, 32, 64);
    l += ts;

    // ---- P -> bf16 A-frag entirely in registers ----
    unsigned w0, w1, w2, w3, w4, w5, w6, w7;
    asm("v_cvt_pk_bf16_f32 %0, %1, %2" : "=v"(w0) : "v"(p_[0]),  "v"(p_[1]));
    asm("v_cvt_pk_bf16_f32 %0, %1, %2" : "=v"(w1) : "v"(p_[2]),  "v"(p_[3]));
    asm("v_cvt_pk_bf16_f32 %0, %1, %2" : "=v"(w2) : "v"(p_[4]),  "v"(p_[5]));
    asm("v_cvt_pk_bf16_f32 %0, %1, %2" : "=v"(w3) : "v"(p_[6]),  "v"(p_[7]));
    asm("v_cvt_pk_bf16_f32 %0, %1, %2" : "=v"(w4) : "v"(p_[8]),  "v"(p_[9]));
    asm("v_cvt_pk_bf16_f32 %0, %1, %2" : "=v"(w5) : "v"(p_[10]), "v"(p_[11]));
    asm("v_cvt_pk_bf16_f32 %0, %1, %2" : "=v"(w6) : "v"(p_[12]), "v"(p_[13]));
    asm("v_cvt_pk_bf16_f32 %0, %1, %2" : "=v"(w7) : "v"(p_[14]), "v"(p_[15]));
    asm("v_permlane32_swap_b32 %0, %1" : "+v"(w0), "+v"(w2));
    asm("v_permlane32_swap_b32 %0, %1" : "+v"(w1), "+v"(w3));
    asm("v_permlane32_swap_b32 %0, %1" : "+v"(w4), "+v"(w6));
    asm("v_permlane32_swap_b32 %0, %1" : "+v"(w5), "+v"(w7));
    short8 pf0 = __builtin_bit_cast(short8, (u32x4){w0, w1, w2, w3});  // kv 0..15
    short8 pf1 = __builtin_bit_cast(short8, (u32x4){w4, w5, w6, w7});  // kv 16..31

    // ---- PV: oacc[dt] += mfma(V^T-frag(d rows), P-frag(q rows)) ----
    #pragma unroll
    for (int dt = 0; dt < 8; ++dt) {
      unsigned vrow = (dt * 32u + q) * 64u;
      short8 vf0 = *(const short8*)(vl + vrow + ((hi * 16u) ^ vx));
      short8 vf1 = *(const short8*)(vl + vrow + ((32u + hi * 16u) ^ vx));
      oacc[dt] = __builtin_amdgcn_mfma_f32_32x32x16_bf16(vf0, pf0, oacc[dt], 0, 0, 0);
      oacc[dt] = __builtin_amdgcn_mfma_f32_32x32x16_bf16(vf1, pf1, oacc[dt], 0, 0, 0);
    }
    __syncthreads();   // next tile staged & visible; all reads of buf done
    buf ^= 1;
  }

  // ---- combine the two kv-halves; everything per-lane (q-local) ----
  float* lmm = (float*)(smem + 100352);
  float* lml = lmm + 128;
  if (lane < 32) { lmm[(qs * 2 + h) * 32 + q] = m; lml[(qs * 2 + h) * 32 + q] = l; }
  __syncthreads();
  float mo = lmm[(qs * 2 + (h ^ 1)) * 32 + q];
  float lo = lml[(qs * 2 + (h ^ 1)) * 32 + q];
  float M = fmaxf(m, mo);
  float al = __expf(m - M);
  float Lf = l * al + lo * __expf(mo - M);
  float iL = 1.f / Lf;

  float* sc32 = (float*)smem;                // [qs][32 q][257w] f32
  short* sc16 = (short*)(smem + 66560);      // [qs][32 q][258]  bf16
  if (h == 0) {
    #pragma unroll
    for (int dt = 0; dt < 8; ++dt)
      #pragma unroll
      for (int r = 0; r < 16; ++r) {
        int d = dt * 32 + (r & 3) + 8 * (r >> 2) + 4 * hi;
        sc32[qs * 8224 + q * 257 + d] = oacc[dt][r] * al;
      }
  }
  __syncthreads();
  if (h == 1) {
    #pragma unroll
    for (int dt = 0; dt < 8; ++dt)
      #pragma unroll
      for (int r = 0; r < 16; ++r) {
        int d = dt * 32 + (r & 3) + 8 * (r >> 2) + 4 * hi;
        float v = (sc32[qs * 8224 + q * 257 + d] + oacc[dt][r] * al) * iL;
        sc16[qs * 8256 + q * 258 + d] = f2b(v);
      }
  }
  __syncthreads();
  // cooperative coalesced copy to global
  {
    int row = t >> 2;                        // 0..63 = qs*32+q
    const short* src = sc16 + (row >> 5) * 8256 + (row & 31) * 258 + (t & 3) * 64;
    short* dst = ob + ((size_t)b * NPOS + q0 + row) * DIM + (t & 3) * 64;
    #pragma unroll
    for (int j = 0; j < 8; ++j)
      *(short8*)(dst + j * 8) = *(const short8*)(src + j * 8);
  }
}

extern "C" void kernel_launch(void* const* d_in, const int* in_sizes, int n_in,
                              void* d_out, int out_size, void* d_ws, size_t ws_size,
                              hipStream_t stream) {
  const float* x     = (const float*)d_in[0];
  const float* gamma = (const float*)d_in[1];
  const float* beta  = (const float*)d_in[2];
  const float* wqkv  = (const float*)d_in[3];
  const float* bqkv  = (const float*)d_in[4];
  const float* wproj = (const float*)d_in[5];
  const float* bproj = (const float*)d_in[6];
  float* out = (float*)d_out;

  char* ws = (char*)d_ws;
  float* stats = (float*)ws;
  short* wqb = (short*)(ws + 1024);
  short* wpb = (short*)(ws + 1024 + 393216);
  size_t off = 1024 + 393216 + 131072;
  const size_t SZ = (size_t)NB * NPOS * DIM * sizeof(short);  // 8 MB
  short* ht   = (short*)(ws + off); off += SZ;
  short* qbuf = (short*)(ws + off); off += SZ;
  short* kbuf = (short*)(ws + off); off += SZ;
  short* vtb  = (short*)(ws + off); off += SZ;
  short* obuf = ht;  // h_t dead after QKV gemm; reuse for attention output

  k_convert_w<<<768, 256, 0, stream>>>(wqkv, wproj, wqb, wpb);
  k_gn_stats<<<128, 256, 0, stream>>>(x, stats);
  k_gn_apply<<<dim3(4, 64, NB), 256, 0, stream>>>(x, stats, gamma, beta, ht);
  k_gemm<0><<<dim3(32, 6, NB), 256, 0, stream>>>(ht, wqb, bqkv, qbuf, kbuf, vtb, nullptr, nullptr);
  k_flash<<<dim3(256), 256, 0, stream>>>(qbuf, kbuf, vtb, obuf);
  k_gemm<1><<<dim3(2, 32, NB), 256, 0, stream>>>(wpb, obuf, bproj, nullptr, nullptr, nullptr, x, out);
}